// Round 25
// baseline (1223.269 us; speedup 1.0000x reference)
//
#include <hip/hip_runtime.h>
#include <hip/hip_bf16.h>
#include <math.h>

#define ISZ 256
#define KSEL 31      // keep top-(K+1) = 31
#define CMIN 64      // min candidate count
#define CEXIT 600    // cleanup bisection window top
#define CAP 768      // per-row candidate cap (R22 fix: 384 -> 768, kills overflow tail)
#define NSEL 64      // slow-path fp64 prefilter size
#define NBL 64       // borderline cap
#define WIN 4e-3f    // borderline half-width (proven R19-R24)
#define ZQ 2.0f      // prepass thr = mean + ZQ*sd (~230 cands median)
#define NSAMP 128
#define SSTR 78      // 127*78 = 9906 < 10000
// legacy small-ws fallback constants (R21 proven)
#define NCANDF 320
#define CEXITF 192
#define ZSTATF 2.25f

typedef __attribute__((ext_vector_type(8))) short bf16x8;
typedef __attribute__((ext_vector_type(4))) float f32x4;

__device__ __forceinline__ double h64_of(float f, float w0, float w1) {
    return fmax((double)f * (double)w0, 0.0) * (double)w1;
}

// ---------------- embedding (proven verbatim) ----------------
__global__ __launch_bounds__(256) void emb_kernel(const float* __restrict__ F,
                                                  const float* __restrict__ w0,
                                                  const float* __restrict__ w1,
                                                  __hip_bfloat16* __restrict__ Eb,
                                                  double* __restrict__ snorm,
                                                  int n) {
    int row = blockIdx.x;
    int t = threadIdx.x;
    float f = F[(size_t)row * ISZ + t];
    double h64 = h64_of(f, w0[t], w1[t]);
    double ss = h64 * h64;
#pragma unroll
    for (int off = 32; off; off >>= 1) ss += __shfl_down(ss, off);
    __shared__ double red[4];
    if ((t & 63) == 0) red[t >> 6] = ss;
    __syncthreads();
    double tot = red[0] + red[1] + red[2] + red[3];
    double s = fmax(sqrt(tot), 1e-12);
    if (t == 0) snorm[row] = s;
    Eb[(size_t)row * ISZ + t] = __float2bfloat16((float)(h64 / s));
}

// ---------------- sample pack + per-row threshold (R22 proven) ----------------
__global__ __launch_bounds__(256) void pack_samples(const __hip_bfloat16* __restrict__ Eb,
                                                    __hip_bfloat16* __restrict__ EbS, int n) {
    int s = blockIdx.x;
    int t = threadIdx.x;
    EbS[t * NSAMP + s] = Eb[(size_t)(s * SSTR) * ISZ + t];
}

__global__ __launch_bounds__(128) void prepass_t0(const __hip_bfloat16* __restrict__ Eb,
                                                  const __hip_bfloat16* __restrict__ EbS,
                                                  float* __restrict__ t0arr, int n) {
    __shared__ float hrow[ISZ];
    __shared__ float reda[2], redb[2];
    __shared__ int redc[2];
    int row = blockIdx.x, t = threadIdx.x;
    hrow[t] = __bfloat162float(Eb[(size_t)row * ISZ + t]);
    hrow[t + 128] = __bfloat162float(Eb[(size_t)row * ISZ + t + 128]);
    __syncthreads();
    int samp = t * SSTR;
    float acc = 0.0f;
    for (int e = 0; e < ISZ; ++e)
        acc += hrow[e] * __bfloat162float(EbS[e * NSAMP + t]);
    bool ex = (samp == row);
    float a = ex ? 0.0f : acc, a2 = ex ? 0.0f : acc * acc;
    int c = ex ? 0 : 1;
#pragma unroll
    for (int off = 32; off; off >>= 1) {
        a += __shfl_down(a, off);
        a2 += __shfl_down(a2, off);
        c += __shfl_down(c, off);
    }
    int w = t >> 6;
    if ((t & 63) == 0) { reda[w] = a; redb[w] = a2; redc[w] = c; }
    __syncthreads();
    if (t == 0) {
        float S = reda[0] + reda[1], S2 = redb[0] + redb[1];
        int C = redc[0] + redc[1];
        float mean = S / (float)C;
        float var = fmaxf(S2 / (float)C - mean * mean, 1e-8f);
        t0arr[row] = mean + ZQ * sqrtf(var);
    }
}

// ---------------- fused gemm + candidate scan (R22 proven, no sim store) ----------------
__global__ __launch_bounds__(256) void gemm_scan(const __hip_bfloat16* __restrict__ Eb,
                                                 const float* __restrict__ t0arr,
                                                 int* __restrict__ cnt,
                                                 int2* __restrict__ buf, int n) {
    int bx = blockIdx.x, by = blockIdx.y;
    if (bx < by) return;
    __shared__ float lds[4][64][65];
    int row0 = by * 128, col0 = bx * 128;
    int tid = threadIdx.x, lane = tid & 63, wid = tid >> 6;
    int wr = wid >> 1, wc = wid & 1;
    int rbase = row0 + wr * 64 + (lane & 15);
    int cbase = col0 + wc * 64 + (lane & 15);
    int kg2 = ((lane >> 4) * 8) * 2;
    const char* Ep = (const char*)Eb;
    unsigned aoff[4], boff[4];
#pragma unroll
    for (int i = 0; i < 4; ++i) {
        aoff[i] = (unsigned)min(rbase + i * 16, n - 1) * (ISZ * 2) + kg2;
        boff[i] = (unsigned)min(cbase + i * 16, n - 1) * (ISZ * 2) + kg2;
    }
    f32x4 acc[4][4] = {};
#pragma unroll
    for (int kt = 0; kt < ISZ; kt += 32) {
        bf16x8 a[4], b[4];
#pragma unroll
        for (int i = 0; i < 4; ++i) a[i] = *(const bf16x8*)(Ep + aoff[i] + kt * 2);
#pragma unroll
        for (int j = 0; j < 4; ++j) b[j] = *(const bf16x8*)(Ep + boff[j] + kt * 2);
#pragma unroll
        for (int i = 0; i < 4; ++i)
#pragma unroll
            for (int j = 0; j < 4; ++j)
                acc[i][j] = __builtin_amdgcn_mfma_f32_16x16x32_bf16(a[i], b[j], acc[i][j], 0, 0, 0);
    }
    float (*T)[65] = lds[wid];   // wave-private, no barriers
#pragma unroll
    for (int i = 0; i < 4; ++i)
#pragma unroll
        for (int j = 0; j < 4; ++j)
#pragma unroll
            for (int r = 0; r < 4; ++r)
                T[(lane >> 4) * 4 + i * 16 + r][(lane & 15) + j * 16] = acc[i][j][r];
    int gr0 = row0 + wr * 64;
    int gc0 = col0 + wc * 64;
    // row-direction scan: lane owns row gr0+lane; banks (lane+c)%32 -> 2-way, free
    {
        int gr = gr0 + lane;
        if (gr < n) {
            float t0r = t0arr[gr];
            int cmax = min(64, n - gc0);
            for (int c = 0; c < cmax; ++c) {
                float x = T[lane][c];
                if (x >= t0r) {
                    int pos = atomicAdd(&cnt[gr], 1);
                    if (pos < CAP) buf[(size_t)gr * CAP + pos] = make_int2(gc0 + c, __float_as_int(x));
                }
            }
        }
    }
    // mirror scan (bx>by): lane owns column lane -> row gc0+lane of the mirror
    if (bx > by) {
        int gr2 = gc0 + lane;
        if (gr2 < n) {
            float t0r = t0arr[gr2];
            int rmax = min(64, n - gr0);
            for (int r = 0; r < rmax; ++r) {
                float x = T[r][lane];
                if (x >= t0r) {
                    int pos = atomicAdd(&cnt[gr2], 1);
                    if (pos < CAP) buf[(size_t)gr2 * CAP + pos] = make_int2(gr0 + r, __float_as_int(x));
                }
            }
        }
    }
}

// ---------------- deterministic rebuild of count-window misses (rare) ----------------
__global__ __launch_bounds__(256) void cleanup(const __hip_bfloat16* __restrict__ Eb,
                                               int* __restrict__ cnt,
                                               int2* __restrict__ buf, int n) {
    int row = blockIdx.x;
    int c0 = cnt[row];
    if (c0 >= CMIN && c0 <= CAP) return;
    __shared__ float hrow[ISZ];
    __shared__ int redi[4];
    __shared__ int lcnt;
    int tid = threadIdx.x, lane = tid & 63, wid = tid >> 6;
    hrow[tid] = __bfloat162float(Eb[(size_t)row * ISZ + tid]);
    if (tid == 0) lcnt = 0;
    __syncthreads();
    float v[40];
    for (int s = 0; s < 40; ++s) {
        int col = tid + 256 * s;
        if (col < n) {
            float acc = 0.0f;
            for (int e = 0; e < ISZ; ++e)
                acc += hrow[e] * __bfloat162float(Eb[(size_t)col * ISZ + e]);
            v[s] = acc;
        } else v[s] = -1e30f;
    }
    auto blockcount = [&](float tt) -> int {
        int c = 0;
#pragma unroll
        for (int q = 0; q < 40; ++q) c += (v[q] >= tt) ? 1 : 0;
#pragma unroll
        for (int off = 32; off; off >>= 1) c += __shfl_down(c, off);
        if (lane == 0) redi[wid] = c;
        __syncthreads();
        int tot = redi[0] + redi[1] + redi[2] + redi[3];
        __syncthreads();
        return tot;
    };
    float lo = 0.0f, hi = 1.01f, thr = 0.0f;
    bool found = false;
    for (int it = 0; it < 30 && !found; ++it) {
        float mid = 0.5f * (lo + hi);
        int c = blockcount(mid);
        if (c >= CMIN && c <= CEXIT) { thr = mid; found = true; }
        else if (c >= CMIN) lo = mid;
        else hi = mid;
    }
    if (!found) thr = lo;
    for (int s = 0; s < 40; ++s) {
        if (v[s] >= thr) {
            int pos = atomicAdd(&lcnt, 1);
            if (pos < CAP)
                buf[(size_t)row * CAP + pos] = make_int2(tid + 256 * s, __float_as_int(v[s]));
        }
    }
    __syncthreads();
    if (tid == 0) cnt[row] = min(lcnt, CAP);
}

// ---------------- candidate-only select + fused zeroing (R22 proven phases) ----------------
__global__ __launch_bounds__(256, 8) void select_k(float* __restrict__ OUT,
                                                   const float* __restrict__ F,
                                                   const float* __restrict__ W0,
                                                   const float* __restrict__ W1,
                                                   const double* __restrict__ snorm,
                                                   const int* __restrict__ cnt,
                                                   const int2* __restrict__ buf,
                                                   int n) {
    __shared__ int cidx[CAP];
    __shared__ float csim[CAP];
    __shared__ int selc[NSEL];
    __shared__ int blist[NBL];
    __shared__ double cand_val[NSEL];
    __shared__ int rankarr[NSEL];
    __shared__ int nhi_s, nbl_s;
    __shared__ float s31_s;
    int row = blockIdx.x, tid = threadIdx.x;
    int lane = tid & 63, wid = tid >> 6;
    float* outp = OUT + (size_t)row * n;

    int m = cnt[row];
    if (m > CAP) m = CAP;   // safety (cleanup guarantees window)
    for (int i = tid; i < m; i += 256) {
        int2 p = buf[(size_t)row * CAP + i];
        cidx[i] = p.x;
        csim[i] = __int_as_float(p.y);
    }
    // zero the output row (independent stream, overlaps everything below)
    {
        float4 z4 = make_float4(0.f, 0.f, 0.f, 0.f);
        for (int e = 4 * tid; e < n; e += 1024) *(float4*)(outp + e) = z4;
    }
    if (tid == 0) { nhi_s = 0; nbl_s = 0; }
    __syncthreads();

    // ---- stored-fp32 lex rank -> selc top-NSEL + s31 ----
    for (int c = tid; c < m; c += 256) {
        float mys = csim[c]; int myi = cidx[c]; int r = 0;
        for (int j = 0; j < m; ++j) {
            float vj = csim[j];
            r += (vj > mys || (vj == mys && cidx[j] < myi)) ? 1 : 0;
        }
        if (r < NSEL) selc[r] = c;
        if (r == KSEL - 1) s31_s = mys;
    }
    __syncthreads();
    float s31 = s31_s;

    // ---- classify: definite-in / borderline band ----
    for (int c = tid; c < m; c += 256) {
        float sc = csim[c];
        if (sc > s31 + WIN) atomicAdd(&nhi_s, 1);
        else if (sc >= s31 - WIN) { int p = atomicAdd(&nbl_s, 1); if (p < NBL) blist[p] = c; }
    }
    __syncthreads();
    int nhi = nhi_s, nblv = nbl_s;
    bool fastB = (nblv <= NBL);
    int mm = fastB ? nblv : min(m, NSEL);
    int kneed = KSEL - nhi;

    // ---- fp64 recompute over L = fastB ? blist : selc (4-way ILP) ----
    double hr[4];
    float w0e[4], w1e[4];
#pragma unroll
    for (int r = 0; r < 4; ++r) {
        int e = lane + 64 * r;
        w0e[r] = W0[e];
        w1e[r] = W1[e];
        hr[r] = h64_of(F[(size_t)row * ISZ + e], w0e[r], w1e[r]);
    }
    double srow = snorm[row];
    for (int s = wid * 4; s < mm; s += 16) {
        int l0 = fastB ? blist[s] : selc[s];
        int l1 = fastB ? blist[min(s + 1, mm - 1)] : selc[min(s + 1, mm - 1)];
        int l2 = fastB ? blist[min(s + 2, mm - 1)] : selc[min(s + 2, mm - 1)];
        int l3 = fastB ? blist[min(s + 3, mm - 1)] : selc[min(s + 3, mm - 1)];
        int j0 = cidx[l0], j1 = cidx[l1], j2 = cidx[l2], j3 = cidx[l3];
        double a0 = 0.0, a1 = 0.0, a2 = 0.0, a3 = 0.0;
#pragma unroll
        for (int r = 0; r < 4; ++r) {
            int e = lane + 64 * r;
            float f0 = F[(size_t)j0 * ISZ + e];
            float f1 = F[(size_t)j1 * ISZ + e];
            float f2 = F[(size_t)j2 * ISZ + e];
            float f3 = F[(size_t)j3 * ISZ + e];
            a0 += hr[r] * h64_of(f0, w0e[r], w1e[r]);
            a1 += hr[r] * h64_of(f1, w0e[r], w1e[r]);
            a2 += hr[r] * h64_of(f2, w0e[r], w1e[r]);
            a3 += hr[r] * h64_of(f3, w0e[r], w1e[r]);
        }
#pragma unroll
        for (int off = 32; off; off >>= 1) {
            a0 += __shfl_down(a0, off);
            a1 += __shfl_down(a1, off);
            a2 += __shfl_down(a2, off);
            a3 += __shfl_down(a3, off);
        }
        if (lane == 0) {
            cand_val[s] = a0 / (srow * snorm[j0]);
            if (s + 1 < mm) cand_val[s + 1] = a1 / (srow * snorm[j1]);
            if (s + 2 < mm) cand_val[s + 2] = a2 / (srow * snorm[j2]);
            if (s + 3 < mm) cand_val[s + 3] = a3 / (srow * snorm[j3]);
        }
    }
    __syncthreads();

    // ---- exact rank among recomputed (stable lowest-index ties) ----
    for (int s2 = tid; s2 < mm; s2 += 256) {
        int li = fastB ? blist[s2] : selc[s2];
        double vv = cand_val[s2];
        int idx = cidx[li];
        int rank = 0;
        for (int j2 = 0; j2 < mm; ++j2) {
            int lj = fastB ? blist[j2] : selc[j2];
            double vj = cand_val[j2];
            rank += (vj > vv || (vj == vv && cidx[lj] < idx)) ? 1 : 0;
        }
        rankarr[s2] = rank;
    }
    __syncthreads();   // zeros + ranks complete before patches

    if (fastB) {
        for (int c = tid; c < m; c += 256)
            if (csim[c] > s31 + WIN) outp[cidx[c]] = fmaxf(csim[c], 0.0f);
        for (int s2 = tid; s2 < mm; s2 += 256)
            if (rankarr[s2] < kneed)
                outp[cidx[blist[s2]]] = (float)fmax(cand_val[s2], 0.0);
    } else {
        for (int s2 = tid; s2 < mm; s2 += 256)
            if (rankarr[s2] < KSEL)
                outp[cidx[selc[s2]]] = (float)fmax(cand_val[s2], 0.0);
    }
}

// ---------------- R21 small-ws fallback (verbatim) ----------------
__global__ __launch_bounds__(256) void gemm_store(const __hip_bfloat16* __restrict__ Eb,
                                                  float* __restrict__ S, int n) {
    int bx = blockIdx.x, by = blockIdx.y;
    if (bx < by) return;
    __shared__ float lds[4][64][65];
    int row0 = by * 128, col0 = bx * 128;
    int tid = threadIdx.x, lane = tid & 63, wid = tid >> 6;
    int wr = wid >> 1, wc = wid & 1;
    int rbase = row0 + wr * 64 + (lane & 15);
    int cbase = col0 + wc * 64 + (lane & 15);
    int kg2 = ((lane >> 4) * 8) * 2;
    const char* Ep = (const char*)Eb;
    unsigned aoff[4], boff[4];
#pragma unroll
    for (int i = 0; i < 4; ++i) {
        aoff[i] = (unsigned)min(rbase + i * 16, n - 1) * (ISZ * 2) + kg2;
        boff[i] = (unsigned)min(cbase + i * 16, n - 1) * (ISZ * 2) + kg2;
    }
    f32x4 acc[4][4] = {};
#pragma unroll
    for (int kt = 0; kt < ISZ; kt += 32) {
        bf16x8 a[4], b[4];
#pragma unroll
        for (int i = 0; i < 4; ++i) a[i] = *(const bf16x8*)(Ep + aoff[i] + kt * 2);
#pragma unroll
        for (int j = 0; j < 4; ++j) b[j] = *(const bf16x8*)(Ep + boff[j] + kt * 2);
#pragma unroll
        for (int i = 0; i < 4; ++i)
#pragma unroll
            for (int j = 0; j < 4; ++j)
                acc[i][j] = __builtin_amdgcn_mfma_f32_16x16x32_bf16(a[i], b[j], acc[i][j], 0, 0, 0);
    }
    float (*T)[65] = lds[wid];
#pragma unroll
    for (int i = 0; i < 4; ++i)
#pragma unroll
        for (int j = 0; j < 4; ++j)
#pragma unroll
            for (int r = 0; r < 4; ++r)
                T[(lane >> 4) * 4 + i * 16 + r][(lane & 15) + j * 16] = acc[i][j][r];
    int gr0 = row0 + wr * 64;
    int gc0 = col0 + wc * 64;
    int c4 = (lane & 15) * 4;
#pragma unroll
    for (int p = 0; p < 16; ++p) {
        int r = p * 4 + (lane >> 4);
        int gr = gr0 + r;
        if (gr >= n) continue;
        int gc = gc0 + c4;
        float4 w = make_float4(T[r][c4], T[r][c4 + 1], T[r][c4 + 2], T[r][c4 + 3]);
        if (gc + 3 < n) *(float4*)&S[(size_t)gr * n + gc] = w;
        else {
            float wa[4] = {w.x, w.y, w.z, w.w};
#pragma unroll
            for (int q = 0; q < 4; ++q)
                if (gc + q < n) S[(size_t)gr * n + gc + q] = wa[q];
        }
    }
    if (bx > by) {
#pragma unroll
        for (int p = 0; p < 16; ++p) {
            int rp = p * 4 + (lane >> 4);
            int gr2 = gc0 + rp;
            if (gr2 >= n) continue;
            int gc2 = gr0 + c4;
            float4 w = make_float4(T[c4][rp], T[c4 + 1][rp], T[c4 + 2][rp], T[c4 + 3][rp]);
            if (gc2 + 3 < n) *(float4*)&S[(size_t)gr2 * n + gc2] = w;
            else {
                float wa[4] = {w.x, w.y, w.z, w.w};
#pragma unroll
                for (int q = 0; q < 4; ++q)
                    if (gc2 + q < n) S[(size_t)gr2 * n + gc2 + q] = wa[q];
            }
        }
    }
}

__global__ __launch_bounds__(256) void topk_legacy(float* C,
                                                   const float* __restrict__ F,
                                                   const float* __restrict__ W0,
                                                   const float* __restrict__ W1,
                                                   const double* __restrict__ snorm,
                                                   int n) {
    __shared__ unsigned flags[320];
    __shared__ float redf[8];
    __shared__ int redi[4];
    __shared__ int cand_idx[NCANDF];
    __shared__ float csim[NCANDF];
    __shared__ int selc[NSEL];
    __shared__ double cand_val[NSEL];
    __shared__ int rankarr[NSEL];
    __shared__ int ncand;
    __shared__ float thr_sh;
    int row = blockIdx.x;
    int tid = threadIdx.x;
    int lane = tid & 63, wid = tid >> 6;
    float* rowp = C + (size_t)row * n;
    float v[40];
#pragma unroll
    for (int s = 0; s < 10; ++s) {
        int e = 4 * tid + 1024 * s;
        if (e < n) {
            float4 w = *(const float4*)(rowp + e);
            v[s * 4 + 0] = w.x; v[s * 4 + 1] = w.y;
            v[s * 4 + 2] = w.z; v[s * 4 + 3] = w.w;
        } else {
#pragma unroll
            for (int q = 0; q < 4; ++q) v[s * 4 + q] = -1e30f;
        }
    }
    for (int q = tid; q < 320; q += 256) flags[q] = 0;
    if (tid == 0) ncand = 0;
    __syncthreads();
    {
        float s1 = 0.0f, s2 = 0.0f;
#pragma unroll
        for (int s = 0; s < 10; ++s) {
            int e = 4 * tid + 1024 * s;
            if (e < n) {
#pragma unroll
                for (int j = 0; j < 4; ++j) { float x = v[s * 4 + j]; s1 += x; s2 += x * x; }
            }
        }
#pragma unroll
        for (int off = 32; off; off >>= 1) { s1 += __shfl_down(s1, off); s2 += __shfl_down(s2, off); }
        if (lane == 0) { redf[wid] = s1; redf[wid + 4] = s2; }
        __syncthreads();
        if (tid == 0) {
            float S1 = redf[0] + redf[1] + redf[2] + redf[3];
            float S2 = redf[4] + redf[5] + redf[6] + redf[7];
            float mean = S1 / (float)n;
            float var = fmaxf(S2 / (float)n - mean * mean, 1e-12f);
            thr_sh = mean + ZSTATF * sqrtf(var);
        }
        __syncthreads();
    }
    float thr = thr_sh;
    auto blockcount = [&](float t) -> int {
        int c = 0;
#pragma unroll
        for (int q = 0; q < 40; ++q) c += (v[q] >= t) ? 1 : 0;
#pragma unroll
        for (int off = 32; off; off >>= 1) c += __shfl_down(c, off);
        if (lane == 0) redi[wid] = c;
        __syncthreads();
        int tot = redi[0] + redi[1] + redi[2] + redi[3];
        __syncthreads();
        return tot;
    };
    auto collect = [&](float t) {
#pragma unroll
        for (int s = 0; s < 10; ++s) {
            int e = 4 * tid + 1024 * s;
#pragma unroll
            for (int j = 0; j < 4; ++j) {
                float x = v[s * 4 + j];
                if (x >= t) {
                    int pos = atomicAdd(&ncand, 1);
                    if (pos < NCANDF) { cand_idx[pos] = e + j; csim[pos] = x; }
                }
            }
        }
        __syncthreads();
    };
    collect(thr);
    if (ncand < CMIN || ncand > NCANDF) {
        __syncthreads();
        if (tid == 0) ncand = 0;
        __syncthreads();
        float lo = 0.0f, hi = 0.75f;
        thr = 0.0f;
        bool found = false;
        for (int it = 0; it < 30 && !found; ++it) {
            float mid = 0.5f * (lo + hi);
            int c = blockcount(mid);
            if (c >= CMIN && c <= CEXITF) { thr = mid; found = true; }
            else if (c >= CMIN) lo = mid;
            else hi = mid;
        }
        if (!found) thr = lo;
        collect(thr);
    }
    int m = min(ncand, NCANDF);
    for (int c = tid; c < m; c += 256) {
        float mys = csim[c]; int myi = cand_idx[c]; int r = 0;
        for (int j = 0; j < m; ++j) {
            float vj = csim[j];
            r += (vj > mys || (vj == mys && cand_idx[j] < myi)) ? 1 : 0;
        }
        if (r < NSEL) selc[r] = c;
    }
    __syncthreads();
    int mm = min(m, NSEL);
    double hr[4]; float w0e[4], w1e[4];
#pragma unroll
    for (int r = 0; r < 4; ++r) {
        int e = lane + 64 * r;
        w0e[r] = W0[e]; w1e[r] = W1[e];
        hr[r] = h64_of(F[(size_t)row * ISZ + e], w0e[r], w1e[r]);
    }
    double srow = snorm[row];
    for (int s = wid * 4; s < mm; s += 16) {
        int j0 = cand_idx[selc[s]];
        int j1 = cand_idx[selc[min(s + 1, mm - 1)]];
        int j2 = cand_idx[selc[min(s + 2, mm - 1)]];
        int j3 = cand_idx[selc[min(s + 3, mm - 1)]];
        double a0 = 0.0, a1 = 0.0, a2 = 0.0, a3 = 0.0;
#pragma unroll
        for (int r = 0; r < 4; ++r) {
            int e = lane + 64 * r;
            a0 += hr[r] * h64_of(F[(size_t)j0 * ISZ + e], w0e[r], w1e[r]);
            a1 += hr[r] * h64_of(F[(size_t)j1 * ISZ + e], w0e[r], w1e[r]);
            a2 += hr[r] * h64_of(F[(size_t)j2 * ISZ + e], w0e[r], w1e[r]);
            a3 += hr[r] * h64_of(F[(size_t)j3 * ISZ + e], w0e[r], w1e[r]);
        }
#pragma unroll
        for (int off = 32; off; off >>= 1) {
            a0 += __shfl_down(a0, off); a1 += __shfl_down(a1, off);
            a2 += __shfl_down(a2, off); a3 += __shfl_down(a3, off);
        }
        if (lane == 0) {
            cand_val[s] = a0 / (srow * snorm[j0]);
            if (s + 1 < mm) cand_val[s + 1] = a1 / (srow * snorm[j1]);
            if (s + 2 < mm) cand_val[s + 2] = a2 / (srow * snorm[j2]);
            if (s + 3 < mm) cand_val[s + 3] = a3 / (srow * snorm[j3]);
        }
    }
    __syncthreads();
    for (int s2 = tid; s2 < mm; s2 += 256) {
        double vv = cand_val[s2];
        int idx = cand_idx[selc[s2]];
        int rank = 0;
        for (int j2 = 0; j2 < mm; ++j2) {
            double vj = cand_val[j2];
            rank += (vj > vv || (vj == vv && cand_idx[selc[j2]] < idx)) ? 1 : 0;
        }
        rankarr[s2] = rank;
        if (rank < KSEL) atomicOr(&flags[idx >> 5], 1u << (idx & 31));
    }
    __syncthreads();
#pragma unroll
    for (int s = 0; s < 10; ++s) {
        int e = 4 * tid + 1024 * s;
        if (e >= n) continue;
        float vals[4] = {v[s * 4], v[s * 4 + 1], v[s * 4 + 2], v[s * 4 + 3]};
        float o[4];
#pragma unroll
        for (int j = 0; j < 4; ++j) {
            int q = e + j;
            bool keep = (flags[q >> 5] >> (q & 31)) & 1u;
            o[j] = (keep && vals[j] > 0.0f) ? vals[j] : 0.0f;
        }
        *(float4*)(rowp + e) = make_float4(o[0], o[1], o[2], o[3]);
    }
    __syncthreads();
    for (int s2 = tid; s2 < mm; s2 += 256) {
        if (rankarr[s2] < KSEL)
            rowp[cand_idx[selc[s2]]] = (float)fmax(cand_val[s2], 0.0);
    }
}

extern "C" void kernel_launch(void* const* d_in, const int* in_sizes, int n_in,
                              void* d_out, int out_size, void* d_ws, size_t ws_size,
                              hipStream_t stream) {
    const float* F  = (const float*)d_in[0];
    const float* w0 = (const float*)d_in[1];
    const float* w1 = (const float*)d_in[2];
    float* out = (float*)d_out;
    int isz = in_sizes[1];           // 256
    int n = in_sizes[0] / isz;       // 10000

    char* ws = (char*)d_ws;
    size_t o_ebf = 0;
    size_t o_snorm = o_ebf + (size_t)n * ISZ * 2;
    size_t o_ebs = o_snorm + (size_t)n * 8;
    size_t o_t0 = o_ebs + (size_t)ISZ * NSAMP * 2;
    size_t o_cnt = o_t0 + (size_t)n * 4;
    size_t o_buf = (o_cnt + (size_t)n * 4 + 255) & ~(size_t)255;
    size_t need = o_buf + (size_t)n * CAP * 8;          // ~67 MB

    __hip_bfloat16* Ebf = (__hip_bfloat16*)(ws + o_ebf);
    double* snorm = (double*)(ws + o_snorm);

    int nt = (n + 127) / 128;
    emb_kernel<<<n, 256, 0, stream>>>(F, w0, w1, Ebf, snorm, n);
    if (ws_size >= need) {
        __hip_bfloat16* EbS = (__hip_bfloat16*)(ws + o_ebs);
        float* t0arr = (float*)(ws + o_t0);
        int* cnt = (int*)(ws + o_cnt);
        int2* buf = (int2*)(ws + o_buf);
        hipMemsetAsync(cnt, 0, (size_t)n * 4, stream);
        pack_samples<<<NSAMP, 256, 0, stream>>>(Ebf, EbS, n);
        prepass_t0<<<n, 128, 0, stream>>>(Ebf, EbS, t0arr, n);
        gemm_scan<<<dim3(nt, nt), 256, 0, stream>>>(Ebf, t0arr, cnt, buf, n);
        cleanup<<<n, 256, 0, stream>>>(Ebf, cnt, buf, n);
        select_k<<<n, 256, 0, stream>>>(out, F, w0, w1, snorm, cnt, buf, n);
    } else {
        gemm_store<<<dim3(nt, nt), 256, 0, stream>>>(Ebf, out, n);
        topk_legacy<<<n, 256, 0, stream>>>(out, F, w0, w1, snorm, n);
    }
}

// Round 26
// 475.800 us; speedup vs baseline: 2.5710x; 2.5710x over previous
//
#include <hip/hip_runtime.h>
#include <hip/hip_bf16.h>
#include <math.h>

#define ISZ 256
#define KSEL 31      // keep top-(K+1) = 31
#define CMIN 64      // min candidate count
#define CEXIT 192    // bisection-fallback window top
#define NCAND 320    // candidate cap
#define NSEL 64      // slow-path fp64 prefilter size
#define NBL 64       // borderline cap
#define WINB 6e-3f   // borderline half-width, bf16 sims (>= 2x(quant 2e-3 + gemm 3e-4))
#define WINF 4e-3f   // borderline half-width, fp32 sims (R19-proven)
#define ZSTAT 2.25f  // thr = mean + ZSTAT*sd (~120 cands)
#define FXS 16777216.0  // 2^24 fixed-point scale for deterministic stats

typedef __attribute__((ext_vector_type(8))) short bf16x8;
typedef __attribute__((ext_vector_type(4))) float f32x4;

__device__ __forceinline__ double h64_of(float f, float w0, float w1) {
    return fmax((double)f * (double)w0, 0.0) * (double)w1;
}
__device__ __forceinline__ unsigned short f2bf(float x) {   // RNE
    unsigned u = __float_as_uint(x);
    return (unsigned short)((u + 0x7FFFu + ((u >> 16) & 1u)) >> 16);
}
__device__ __forceinline__ float bf2f(unsigned short u) {
    return __uint_as_float(((unsigned)u) << 16);
}

// ---------------- embedding (proven verbatim) ----------------
__global__ __launch_bounds__(256) void emb_kernel(const float* __restrict__ F,
                                                  const float* __restrict__ w0,
                                                  const float* __restrict__ w1,
                                                  __hip_bfloat16* __restrict__ Eb,
                                                  double* __restrict__ snorm,
                                                  int n) {
    int row = blockIdx.x;
    int t = threadIdx.x;
    float f = F[(size_t)row * ISZ + t];
    double h64 = h64_of(f, w0[t], w1[t]);
    double ss = h64 * h64;
#pragma unroll
    for (int off = 32; off; off >>= 1) ss += __shfl_down(ss, off);
    __shared__ double red[4];
    if ((t & 63) == 0) red[t >> 6] = ss;
    __syncthreads();
    double tot = red[0] + red[1] + red[2] + red[3];
    double s = fmax(sqrt(tot), 1e-12);
    if (t == 0) snorm[row] = s;
    Eb[(size_t)row * ISZ + t] = __float2bfloat16((float)(h64 / s));
}

// ---------------- symmetric MFMA gemm -> bf16 sims + int64 fixed-point stats ----------------
__global__ __launch_bounds__(256) void gemm_bf(const __hip_bfloat16* __restrict__ Eb,
                                               unsigned short* __restrict__ S,
                                               unsigned long long* __restrict__ rsum,
                                               unsigned long long* __restrict__ rsumsq,
                                               int n) {
    int bx = blockIdx.x, by = blockIdx.y;
    if (bx < by) return;
    __shared__ float lds[4][64][65];
    int row0 = by * 128, col0 = bx * 128;
    int tid = threadIdx.x, lane = tid & 63, wid = tid >> 6;
    int wr = wid >> 1, wc = wid & 1;
    int rbase = row0 + wr * 64 + (lane & 15);
    int cbase = col0 + wc * 64 + (lane & 15);
    int kg2 = ((lane >> 4) * 8) * 2;
    const char* Ep = (const char*)Eb;
    unsigned aoff[4], boff[4];
#pragma unroll
    for (int i = 0; i < 4; ++i) {
        aoff[i] = (unsigned)min(rbase + i * 16, n - 1) * (ISZ * 2) + kg2;
        boff[i] = (unsigned)min(cbase + i * 16, n - 1) * (ISZ * 2) + kg2;
    }
    f32x4 acc[4][4] = {};
#pragma unroll
    for (int kt = 0; kt < ISZ; kt += 32) {
        bf16x8 a[4], b[4];
#pragma unroll
        for (int i = 0; i < 4; ++i) a[i] = *(const bf16x8*)(Ep + aoff[i] + kt * 2);
#pragma unroll
        for (int j = 0; j < 4; ++j) b[j] = *(const bf16x8*)(Ep + boff[j] + kt * 2);
#pragma unroll
        for (int i = 0; i < 4; ++i)
#pragma unroll
            for (int j = 0; j < 4; ++j)
                acc[i][j] = __builtin_amdgcn_mfma_f32_16x16x32_bf16(a[i], b[j], acc[i][j], 0, 0, 0);
    }
    float (*T)[65] = lds[wid];   // wave-private
#pragma unroll
    for (int i = 0; i < 4; ++i)
#pragma unroll
        for (int j = 0; j < 4; ++j)
#pragma unroll
            for (int r = 0; r < 4; ++r)
                T[(lane >> 4) * 4 + i * 16 + r][(lane & 15) + j * 16] = acc[i][j][r];
    int gr0 = row0 + wr * 64;
    int gc0 = col0 + wc * 64;
    int c4 = (lane & 15) * 4;
    // (by,bx) tile: quad (16 lanes) writes 64 bf16 = 128 B contiguous
#pragma unroll
    for (int p = 0; p < 16; ++p) {
        int r = p * 4 + (lane >> 4);
        int gr = gr0 + r;
        if (gr >= n) continue;
        int gc = gc0 + c4;
        unsigned short h0 = f2bf(T[r][c4 + 0]), h1 = f2bf(T[r][c4 + 1]);
        unsigned short h2 = f2bf(T[r][c4 + 2]), h3 = f2bf(T[r][c4 + 3]);
        if (gc + 3 < n) {
            uint2 u; u.x = (unsigned)h0 | ((unsigned)h1 << 16);
            u.y = (unsigned)h2 | ((unsigned)h3 << 16);
            *(uint2*)&S[(size_t)gr * n + gc] = u;
        } else {
            unsigned short hh[4] = {h0, h1, h2, h3};
#pragma unroll
            for (int q = 0; q < 4; ++q)
                if (gc + q < n) S[(size_t)gr * n + gc + q] = hh[q];
        }
    }
    // row stats (fp32 tile values, int64 fixed-point -> deterministic)
    {
        int gr = gr0 + lane;
        if (gr < n) {
            float s1 = 0.0f, s2 = 0.0f;
            int cmax = min(64, n - gc0);
            for (int c = 0; c < cmax; ++c) { float x = T[lane][c]; s1 += x; s2 += x * x; }
            if (cmax > 0) {
                long long q1 = (long long)llrintf(s1 * (float)FXS);
                long long q2 = (long long)llrintf(s2 * (float)FXS);
                atomicAdd(&rsum[gr], (unsigned long long)q1);
                atomicAdd(&rsumsq[gr], (unsigned long long)q2);
            }
        }
    }
    if (bx > by) {
#pragma unroll
        for (int p = 0; p < 16; ++p) {
            int rp = p * 4 + (lane >> 4);
            int gr2 = gc0 + rp;
            if (gr2 >= n) continue;
            int gc2 = gr0 + c4;
            unsigned short h0 = f2bf(T[c4 + 0][rp]), h1 = f2bf(T[c4 + 1][rp]);
            unsigned short h2 = f2bf(T[c4 + 2][rp]), h3 = f2bf(T[c4 + 3][rp]);
            if (gc2 + 3 < n) {
                uint2 u; u.x = (unsigned)h0 | ((unsigned)h1 << 16);
                u.y = (unsigned)h2 | ((unsigned)h3 << 16);
                *(uint2*)&S[(size_t)gr2 * n + gc2] = u;
            } else {
                unsigned short hh[4] = {h0, h1, h2, h3};
#pragma unroll
                for (int q = 0; q < 4; ++q)
                    if (gc2 + q < n) S[(size_t)gr2 * n + gc2 + q] = hh[q];
            }
        }
        int gr2 = gc0 + lane;
        if (gr2 < n) {
            float s1 = 0.0f, s2 = 0.0f;
            int rmax = min(64, n - gr0);
            for (int r = 0; r < rmax; ++r) { float x = T[r][lane]; s1 += x; s2 += x * x; }
            if (rmax > 0) {
                long long q1 = (long long)llrintf(s1 * (float)FXS);
                long long q2 = (long long)llrintf(s2 * (float)FXS);
                atomicAdd(&rsum[gr2], (unsigned long long)q1);
                atomicAdd(&rsumsq[gr2], (unsigned long long)q2);
            }
        }
    }
}

// R24-proven topk on bf16 sims + fused zeroing. thr is bit-deterministic
// (int64 stats). Collect -> stored lex rank -> borderline-band (WINB) fp64
// -> exact rank -> patches. d_out zeroed in-kernel.
__global__ __launch_bounds__(256, 8) void topk_bf(const unsigned short* __restrict__ SIM,
                                                  float* __restrict__ OUT,
                                                  const float* __restrict__ F,
                                                  const float* __restrict__ W0,
                                                  const float* __restrict__ W1,
                                                  const double* __restrict__ snorm,
                                                  const unsigned long long* __restrict__ rsum,
                                                  const unsigned long long* __restrict__ rsumsq,
                                                  int n) {
    __shared__ int redi[4];
    __shared__ int cand_idx[NCAND];
    __shared__ float csim[NCAND];
    __shared__ int selc[NSEL];
    __shared__ int blist[NBL];
    __shared__ double cand_val[NSEL];
    __shared__ int rankarr[NSEL];
    __shared__ int ncand, nhi_s, nbl_s;
    __shared__ float s31_s;
    int row = blockIdx.x;
    int tid = threadIdx.x;
    int lane = tid & 63, wid = tid >> 6;
    const unsigned short* simp = SIM + (size_t)row * n;
    float* outp = OUT + (size_t)row * n;

    long long rs = (long long)rsum[row];
    long long rq = (long long)rsumsq[row];

    // zero the output row (independent stream)
    {
        float4 z4 = make_float4(0.f, 0.f, 0.f, 0.f);
#pragma unroll
        for (int s = 0; s < 10; ++s) {
            int e = 4 * tid + 1024 * s;
            if (e < n) *(float4*)(outp + e) = z4;
        }
    }
    // load bf16 row into registers (8 per 16B load; n % 8 == 0)
    float v[40];
#pragma unroll
    for (int s = 0; s < 5; ++s) {
        int e = 8 * tid + 2048 * s;
        if (e < n) {
            uint4 w = *(const uint4*)(simp + e);
            unsigned wa[4] = {w.x, w.y, w.z, w.w};
#pragma unroll
            for (int q = 0; q < 4; ++q) {
                v[s * 8 + 2 * q]     = bf2f((unsigned short)(wa[q] & 0xFFFF));
                v[s * 8 + 2 * q + 1] = bf2f((unsigned short)(wa[q] >> 16));
            }
        } else {
#pragma unroll
            for (int q = 0; q < 8; ++q) v[s * 8 + q] = -1e30f;
        }
    }
    if (tid == 0) { ncand = 0; nhi_s = 0; nbl_s = 0; }
    __syncthreads();

    // deterministic thr (int64 fixed-point stats)
    double S1 = (double)rs / FXS, S2 = (double)rq / FXS;
    float mean = (float)(S1 / n);
    float var = fmaxf((float)(S2 / n) - mean * mean, 1e-12f);
    float thr = mean + ZSTAT * sqrtf(var);

    auto blockcount = [&](float t) -> int {
        int c = 0;
#pragma unroll
        for (int q = 0; q < 40; ++q) c += (v[q] >= t) ? 1 : 0;
#pragma unroll
        for (int off = 32; off; off >>= 1) c += __shfl_down(c, off);
        if (lane == 0) redi[wid] = c;
        __syncthreads();
        int tot = redi[0] + redi[1] + redi[2] + redi[3];
        __syncthreads();
        return tot;
    };
    auto collect = [&](float t) {
#pragma unroll
        for (int s = 0; s < 5; ++s) {
            int e = 8 * tid + 2048 * s;
#pragma unroll
            for (int j = 0; j < 8; ++j) {
                float x = v[s * 8 + j];
                if (x >= t) {
                    int pos = atomicAdd(&ncand, 1);
                    if (pos < NCAND) { cand_idx[pos] = e + j; csim[pos] = x; }
                }
            }
        }
        __syncthreads();
    };

    collect(thr);
    if (ncand < CMIN || ncand > NCAND) {
        __syncthreads();
        if (tid == 0) ncand = 0;
        __syncthreads();
        float lo = 0.0f, hi = 0.75f;
        thr = 0.0f;
        bool found = false;
        for (int it = 0; it < 30 && !found; ++it) {
            float mid = 0.5f * (lo + hi);
            int c = blockcount(mid);
            if (c >= CMIN && c <= CEXIT) { thr = mid; found = true; }
            else if (c >= CMIN) lo = mid;
            else hi = mid;
        }
        if (!found) thr = lo;   // bf16 tie class (~52) < window width -> rare
        collect(thr);
    }
    int m = min(ncand, NCAND);

    for (int c = tid; c < m; c += 256) {
        float mys = csim[c]; int myi = cand_idx[c]; int r = 0;
        for (int j = 0; j < m; ++j) {
            float vj = csim[j];
            r += (vj > mys || (vj == mys && cand_idx[j] < myi)) ? 1 : 0;
        }
        if (r < NSEL) selc[r] = c;
        if (r == KSEL - 1) s31_s = mys;
    }
    __syncthreads();
    float s31 = s31_s;

    for (int c = tid; c < m; c += 256) {
        float sc = csim[c];
        if (sc > s31 + WINB) atomicAdd(&nhi_s, 1);
        else if (sc >= s31 - WINB) { int p = atomicAdd(&nbl_s, 1); if (p < NBL) blist[p] = c; }
    }
    __syncthreads();
    int nhi = nhi_s, nblv = nbl_s;
    bool fastB = (nblv <= NBL);
    int mm = fastB ? nblv : min(m, NSEL);
    int kneed = KSEL - nhi;

    double hr[4];
    float w0e[4], w1e[4];
#pragma unroll
    for (int r = 0; r < 4; ++r) {
        int e = lane + 64 * r;
        w0e[r] = W0[e];
        w1e[r] = W1[e];
        hr[r] = h64_of(F[(size_t)row * ISZ + e], w0e[r], w1e[r]);
    }
    double srow = snorm[row];
    for (int s = wid * 4; s < mm; s += 16) {
        int l0 = fastB ? blist[s] : selc[s];
        int l1 = fastB ? blist[min(s + 1, mm - 1)] : selc[min(s + 1, mm - 1)];
        int l2 = fastB ? blist[min(s + 2, mm - 1)] : selc[min(s + 2, mm - 1)];
        int l3 = fastB ? blist[min(s + 3, mm - 1)] : selc[min(s + 3, mm - 1)];
        int j0 = cand_idx[l0], j1 = cand_idx[l1], j2 = cand_idx[l2], j3 = cand_idx[l3];
        double a0 = 0.0, a1 = 0.0, a2 = 0.0, a3 = 0.0;
#pragma unroll
        for (int r = 0; r < 4; ++r) {
            int e = lane + 64 * r;
            float f0 = F[(size_t)j0 * ISZ + e];
            float f1 = F[(size_t)j1 * ISZ + e];
            float f2 = F[(size_t)j2 * ISZ + e];
            float f3 = F[(size_t)j3 * ISZ + e];
            a0 += hr[r] * h64_of(f0, w0e[r], w1e[r]);
            a1 += hr[r] * h64_of(f1, w0e[r], w1e[r]);
            a2 += hr[r] * h64_of(f2, w0e[r], w1e[r]);
            a3 += hr[r] * h64_of(f3, w0e[r], w1e[r]);
        }
#pragma unroll
        for (int off = 32; off; off >>= 1) {
            a0 += __shfl_down(a0, off);
            a1 += __shfl_down(a1, off);
            a2 += __shfl_down(a2, off);
            a3 += __shfl_down(a3, off);
        }
        if (lane == 0) {
            cand_val[s] = a0 / (srow * snorm[j0]);
            if (s + 1 < mm) cand_val[s + 1] = a1 / (srow * snorm[j1]);
            if (s + 2 < mm) cand_val[s + 2] = a2 / (srow * snorm[j2]);
            if (s + 3 < mm) cand_val[s + 3] = a3 / (srow * snorm[j3]);
        }
    }
    __syncthreads();

    for (int s2 = tid; s2 < mm; s2 += 256) {
        int li = fastB ? blist[s2] : selc[s2];
        double vv = cand_val[s2];
        int idx = cand_idx[li];
        int rank = 0;
        for (int j2 = 0; j2 < mm; ++j2) {
            int lj = fastB ? blist[j2] : selc[j2];
            double vj = cand_val[j2];
            rank += (vj > vv || (vj == vv && cand_idx[lj] < idx)) ? 1 : 0;
        }
        rankarr[s2] = rank;
    }
    __syncthreads();   // zeros + ranks complete before patches

    if (fastB) {
        for (int c = tid; c < m; c += 256)
            if (csim[c] > s31 + WINB) outp[cand_idx[c]] = fmaxf(csim[c], 0.0f);
        for (int s2 = tid; s2 < mm; s2 += 256)
            if (rankarr[s2] < kneed)
                outp[cand_idx[blist[s2]]] = (float)fmax(cand_val[s2], 0.0);
    } else {
        for (int s2 = tid; s2 < mm; s2 += 256)
            if (rankarr[s2] < KSEL)
                outp[cand_idx[selc[s2]]] = (float)fmax(cand_val[s2], 0.0);
    }
}

// ---------------- small-ws fallback: R21-proven fp32 path (verbatim) ----------------
__global__ __launch_bounds__(256) void gemm_store(const __hip_bfloat16* __restrict__ Eb,
                                                  float* __restrict__ S, int n) {
    int bx = blockIdx.x, by = blockIdx.y;
    if (bx < by) return;
    __shared__ float lds[4][64][65];
    int row0 = by * 128, col0 = bx * 128;
    int tid = threadIdx.x, lane = tid & 63, wid = tid >> 6;
    int wr = wid >> 1, wc = wid & 1;
    int rbase = row0 + wr * 64 + (lane & 15);
    int cbase = col0 + wc * 64 + (lane & 15);
    int kg2 = ((lane >> 4) * 8) * 2;
    const char* Ep = (const char*)Eb;
    unsigned aoff[4], boff[4];
#pragma unroll
    for (int i = 0; i < 4; ++i) {
        aoff[i] = (unsigned)min(rbase + i * 16, n - 1) * (ISZ * 2) + kg2;
        boff[i] = (unsigned)min(cbase + i * 16, n - 1) * (ISZ * 2) + kg2;
    }
    f32x4 acc[4][4] = {};
#pragma unroll
    for (int kt = 0; kt < ISZ; kt += 32) {
        bf16x8 a[4], b[4];
#pragma unroll
        for (int i = 0; i < 4; ++i) a[i] = *(const bf16x8*)(Ep + aoff[i] + kt * 2);
#pragma unroll
        for (int j = 0; j < 4; ++j) b[j] = *(const bf16x8*)(Ep + boff[j] + kt * 2);
#pragma unroll
        for (int i = 0; i < 4; ++i)
#pragma unroll
            for (int j = 0; j < 4; ++j)
                acc[i][j] = __builtin_amdgcn_mfma_f32_16x16x32_bf16(a[i], b[j], acc[i][j], 0, 0, 0);
    }
    float (*T)[65] = lds[wid];
#pragma unroll
    for (int i = 0; i < 4; ++i)
#pragma unroll
        for (int j = 0; j < 4; ++j)
#pragma unroll
            for (int r = 0; r < 4; ++r)
                T[(lane >> 4) * 4 + i * 16 + r][(lane & 15) + j * 16] = acc[i][j][r];
    int gr0 = row0 + wr * 64;
    int gc0 = col0 + wc * 64;
    int c4 = (lane & 15) * 4;
#pragma unroll
    for (int p = 0; p < 16; ++p) {
        int r = p * 4 + (lane >> 4);
        int gr = gr0 + r;
        if (gr >= n) continue;
        int gc = gc0 + c4;
        float4 w = make_float4(T[r][c4], T[r][c4 + 1], T[r][c4 + 2], T[r][c4 + 3]);
        if (gc + 3 < n) *(float4*)&S[(size_t)gr * n + gc] = w;
        else {
            float wa[4] = {w.x, w.y, w.z, w.w};
#pragma unroll
            for (int q = 0; q < 4; ++q)
                if (gc + q < n) S[(size_t)gr * n + gc + q] = wa[q];
        }
    }
    if (bx > by) {
#pragma unroll
        for (int p = 0; p < 16; ++p) {
            int rp = p * 4 + (lane >> 4);
            int gr2 = gc0 + rp;
            if (gr2 >= n) continue;
            int gc2 = gr0 + c4;
            float4 w = make_float4(T[c4][rp], T[c4 + 1][rp], T[c4 + 2][rp], T[c4 + 3][rp]);
            if (gc2 + 3 < n) *(float4*)&S[(size_t)gr2 * n + gc2] = w;
            else {
                float wa[4] = {w.x, w.y, w.z, w.w};
#pragma unroll
                for (int q = 0; q < 4; ++q)
                    if (gc2 + q < n) S[(size_t)gr2 * n + gc2 + q] = wa[q];
            }
        }
    }
}

__global__ __launch_bounds__(256) void topk_legacy(float* C,
                                                   const float* __restrict__ F,
                                                   const float* __restrict__ W0,
                                                   const float* __restrict__ W1,
                                                   const double* __restrict__ snorm,
                                                   int n) {
    __shared__ unsigned flags[320];
    __shared__ float redf[8];
    __shared__ int redi[4];
    __shared__ int cand_idx[NCAND];
    __shared__ float csim[NCAND];
    __shared__ int selc[NSEL];
    __shared__ int blist[NBL];
    __shared__ double cand_val[NSEL];
    __shared__ int rankarr[NSEL];
    __shared__ int ncand, nhi_s, nbl_s;
    __shared__ float s31_s;
    int row = blockIdx.x;
    int tid = threadIdx.x;
    int lane = tid & 63, wid = tid >> 6;
    float* rowp = C + (size_t)row * n;
    float v[40];
#pragma unroll
    for (int s = 0; s < 10; ++s) {
        int e = 4 * tid + 1024 * s;
        if (e < n) {
            float4 w = *(const float4*)(rowp + e);
            v[s * 4 + 0] = w.x; v[s * 4 + 1] = w.y;
            v[s * 4 + 2] = w.z; v[s * 4 + 3] = w.w;
        } else {
#pragma unroll
            for (int q = 0; q < 4; ++q) v[s * 4 + q] = -1e30f;
        }
    }
    for (int q = tid; q < 320; q += 256) flags[q] = 0;
    if (tid == 0) { ncand = 0; nhi_s = 0; nbl_s = 0; }
    __syncthreads();
    {
        float s1 = 0.0f, s2 = 0.0f;
#pragma unroll
        for (int s = 0; s < 10; ++s) {
            int e = 4 * tid + 1024 * s;
            if (e < n) {
#pragma unroll
                for (int j = 0; j < 4; ++j) { float x = v[s * 4 + j]; s1 += x; s2 += x * x; }
            }
        }
#pragma unroll
        for (int off = 32; off; off >>= 1) { s1 += __shfl_down(s1, off); s2 += __shfl_down(s2, off); }
        if (lane == 0) { redf[wid] = s1; redf[wid + 4] = s2; }
        __syncthreads();
        if (tid == 0) {
            float S1 = redf[0] + redf[1] + redf[2] + redf[3];
            float S2 = redf[4] + redf[5] + redf[6] + redf[7];
            float mean = S1 / (float)n;
            float var = fmaxf(S2 / (float)n - mean * mean, 1e-12f);
            s31_s = mean + ZSTAT * sqrtf(var);
        }
        __syncthreads();
    }
    float thr = s31_s;
    auto blockcount = [&](float t) -> int {
        int c = 0;
#pragma unroll
        for (int q = 0; q < 40; ++q) c += (v[q] >= t) ? 1 : 0;
#pragma unroll
        for (int off = 32; off; off >>= 1) c += __shfl_down(c, off);
        if (lane == 0) redi[wid] = c;
        __syncthreads();
        int tot = redi[0] + redi[1] + redi[2] + redi[3];
        __syncthreads();
        return tot;
    };
    auto collect = [&](float t) {
#pragma unroll
        for (int s = 0; s < 10; ++s) {
            int e = 4 * tid + 1024 * s;
#pragma unroll
            for (int j = 0; j < 4; ++j) {
                float x = v[s * 4 + j];
                if (x >= t) {
                    int pos = atomicAdd(&ncand, 1);
                    if (pos < NCAND) { cand_idx[pos] = e + j; csim[pos] = x; }
                }
            }
        }
        __syncthreads();
    };
    collect(thr);
    if (ncand < CMIN || ncand > NCAND) {
        __syncthreads();
        if (tid == 0) ncand = 0;
        __syncthreads();
        float lo = 0.0f, hi = 0.75f;
        thr = 0.0f;
        bool found = false;
        for (int it = 0; it < 30 && !found; ++it) {
            float mid = 0.5f * (lo + hi);
            int c = blockcount(mid);
            if (c >= CMIN && c <= CEXIT) { thr = mid; found = true; }
            else if (c >= CMIN) lo = mid;
            else hi = mid;
        }
        if (!found) thr = lo;
        collect(thr);
    }
    int m = min(ncand, NCAND);
    for (int c = tid; c < m; c += 256) {
        float mys = csim[c]; int myi = cand_idx[c]; int r = 0;
        for (int j = 0; j < m; ++j) {
            float vj = csim[j];
            r += (vj > mys || (vj == mys && cand_idx[j] < myi)) ? 1 : 0;
        }
        if (r < NSEL) selc[r] = c;
        if (r == KSEL - 1) s31_s = mys;
    }
    __syncthreads();
    float s31 = s31_s;
    for (int c = tid; c < m; c += 256) {
        float sc = csim[c];
        if (sc > s31 + WINF) atomicAdd(&nhi_s, 1);
        else if (sc >= s31 - WINF) { int p = atomicAdd(&nbl_s, 1); if (p < NBL) blist[p] = c; }
    }
    __syncthreads();
    int nhi = nhi_s, nblv = nbl_s;
    bool fastB = (nblv <= NBL);
    int mm = fastB ? nblv : min(m, NSEL);
    int kneed = KSEL - nhi;
    double hr[4]; float w0e[4], w1e[4];
#pragma unroll
    for (int r = 0; r < 4; ++r) {
        int e = lane + 64 * r;
        w0e[r] = W0[e]; w1e[r] = W1[e];
        hr[r] = h64_of(F[(size_t)row * ISZ + e], w0e[r], w1e[r]);
    }
    double srow = snorm[row];
    for (int s = wid * 4; s < mm; s += 16) {
        int l0 = fastB ? blist[s] : selc[s];
        int l1 = fastB ? blist[min(s + 1, mm - 1)] : selc[min(s + 1, mm - 1)];
        int l2 = fastB ? blist[min(s + 2, mm - 1)] : selc[min(s + 2, mm - 1)];
        int l3 = fastB ? blist[min(s + 3, mm - 1)] : selc[min(s + 3, mm - 1)];
        int j0 = cand_idx[l0], j1 = cand_idx[l1], j2 = cand_idx[l2], j3 = cand_idx[l3];
        double a0 = 0.0, a1 = 0.0, a2 = 0.0, a3 = 0.0;
#pragma unroll
        for (int r = 0; r < 4; ++r) {
            int e = lane + 64 * r;
            a0 += hr[r] * h64_of(F[(size_t)j0 * ISZ + e], w0e[r], w1e[r]);
            a1 += hr[r] * h64_of(F[(size_t)j1 * ISZ + e], w0e[r], w1e[r]);
            a2 += hr[r] * h64_of(F[(size_t)j2 * ISZ + e], w0e[r], w1e[r]);
            a3 += hr[r] * h64_of(F[(size_t)j3 * ISZ + e], w0e[r], w1e[r]);
        }
#pragma unroll
        for (int off = 32; off; off >>= 1) {
            a0 += __shfl_down(a0, off); a1 += __shfl_down(a1, off);
            a2 += __shfl_down(a2, off); a3 += __shfl_down(a3, off);
        }
        if (lane == 0) {
            cand_val[s] = a0 / (srow * snorm[j0]);
            if (s + 1 < mm) cand_val[s + 1] = a1 / (srow * snorm[j1]);
            if (s + 2 < mm) cand_val[s + 2] = a2 / (srow * snorm[j2]);
            if (s + 3 < mm) cand_val[s + 3] = a3 / (srow * snorm[j3]);
        }
    }
    __syncthreads();
    int keepthr = fastB ? kneed : KSEL;
    for (int s2 = tid; s2 < mm; s2 += 256) {
        int li = fastB ? blist[s2] : selc[s2];
        double vv = cand_val[s2];
        int idx = cand_idx[li];
        int rank = 0;
        for (int j2 = 0; j2 < mm; ++j2) {
            int lj = fastB ? blist[j2] : selc[j2];
            double vj = cand_val[j2];
            rank += (vj > vv || (vj == vv && cand_idx[lj] < idx)) ? 1 : 0;
        }
        rankarr[s2] = rank;
        if (rank < keepthr) atomicOr(&flags[idx >> 5], 1u << (idx & 31));
    }
    if (fastB) {
        for (int c = tid; c < m; c += 256) {
            if (csim[c] > s31 + WINF) {
                int idx = cand_idx[c];
                atomicOr(&flags[idx >> 5], 1u << (idx & 31));
            }
        }
    }
    __syncthreads();
#pragma unroll
    for (int s = 0; s < 10; ++s) {
        int e = 4 * tid + 1024 * s;
        if (e >= n) continue;
        float vals[4] = {v[s * 4], v[s * 4 + 1], v[s * 4 + 2], v[s * 4 + 3]};
        float o[4];
#pragma unroll
        for (int j = 0; j < 4; ++j) {
            int q = e + j;
            bool keep = (flags[q >> 5] >> (q & 31)) & 1u;
            o[j] = (keep && vals[j] > 0.0f) ? vals[j] : 0.0f;
        }
        *(float4*)(rowp + e) = make_float4(o[0], o[1], o[2], o[3]);
    }
    __syncthreads();
    if (fastB) {
        for (int s2 = tid; s2 < mm; s2 += 256)
            if (rankarr[s2] < kneed)
                rowp[cand_idx[blist[s2]]] = (float)fmax(cand_val[s2], 0.0);
    } else {
        for (int s2 = tid; s2 < mm; s2 += 256)
            if (rankarr[s2] < KSEL)
                rowp[cand_idx[selc[s2]]] = (float)fmax(cand_val[s2], 0.0);
    }
}

extern "C" void kernel_launch(void* const* d_in, const int* in_sizes, int n_in,
                              void* d_out, int out_size, void* d_ws, size_t ws_size,
                              hipStream_t stream) {
    const float* F  = (const float*)d_in[0];
    const float* w0 = (const float*)d_in[1];
    const float* w1 = (const float*)d_in[2];
    float* out = (float*)d_out;
    int isz = in_sizes[1];           // 256
    int n = in_sizes[0] / isz;       // 10000

    char* ws = (char*)d_ws;
    __hip_bfloat16* Ebf = (__hip_bfloat16*)ws;                        // 5.12 MB
    size_t o_snorm = (size_t)n * ISZ * 2;
    double* snorm = (double*)(ws + o_snorm);                          // 80 KB
    size_t o_rs = o_snorm + (size_t)n * 8;
    unsigned long long* rsum = (unsigned long long*)(ws + o_rs);      // 80 KB
    unsigned long long* rsumsq = (unsigned long long*)(ws + o_rs + (size_t)n * 8);
    size_t o_sim = (o_rs + (size_t)n * 16 + 255) & ~(size_t)255;
    size_t need = o_sim + (size_t)n * n * 2;                          // +200 MB

    int nt = (n + 127) / 128;
    emb_kernel<<<n, 256, 0, stream>>>(F, w0, w1, Ebf, snorm, n);
    if (ws_size >= need) {
        unsigned short* S = (unsigned short*)(ws + o_sim);
        hipMemsetAsync(rsum, 0, (size_t)n * 16, stream);
        gemm_bf<<<dim3(nt, nt), 256, 0, stream>>>(Ebf, S, rsum, rsumsq, n);
        topk_bf<<<n, 256, 0, stream>>>(S, out, F, w0, w1, snorm, rsum, rsumsq, n);
    } else {
        gemm_store<<<dim3(nt, nt), 256, 0, stream>>>(Ebf, out, n);
        topk_legacy<<<n, 256, 0, stream>>>(out, F, w0, w1, snorm, n);
    }
}

// Round 27
// 390.768 us; speedup vs baseline: 3.1304x; 1.2176x over previous
//
#include <hip/hip_runtime.h>
#include <hip/hip_bf16.h>
#include <math.h>

#define ISZ 256
#define KSEL 31      // keep top-(K+1) = 31
#define CMIN 64      // min candidate count
#define CEXIT 192    // bisection-fallback window top
#define NCAND 320    // candidate cap
#define NSEL 64      // slow-path fp64 prefilter size
#define NBL 64       // borderline cap
#define WIN 4e-3f    // borderline half-width (>= 2x stored-sim error)
#define ZSTAT 2.25f  // thr = mean + ZSTAT*sd (~120 cands)

typedef __attribute__((ext_vector_type(8))) short bf16x8;
typedef __attribute__((ext_vector_type(4))) float f32x4;

__device__ __forceinline__ double h64_of(float f, float w0, float w1) {
    return fmax((double)f * (double)w0, 0.0) * (double)w1;
}

// ---------------- embedding (proven verbatim) ----------------
__global__ __launch_bounds__(256) void emb_kernel(const float* __restrict__ F,
                                                  const float* __restrict__ w0,
                                                  const float* __restrict__ w1,
                                                  __hip_bfloat16* __restrict__ Eb,
                                                  double* __restrict__ snorm,
                                                  int n) {
    int row = blockIdx.x;
    int t = threadIdx.x;
    float f = F[(size_t)row * ISZ + t];
    double h64 = h64_of(f, w0[t], w1[t]);
    double ss = h64 * h64;
#pragma unroll
    for (int off = 32; off; off >>= 1) ss += __shfl_down(ss, off);
    __shared__ double red[4];
    if ((t & 63) == 0) red[t >> 6] = ss;
    __syncthreads();
    double tot = red[0] + red[1] + red[2] + red[3];
    double s = fmax(sqrt(tot), 1e-12);
    if (t == 0) snorm[row] = s;
    Eb[(size_t)row * ISZ + t] = __float2bfloat16((float)(h64 / s));
}

// ---------------- symmetric MFMA gemm + row stats (R17/R23 proven) ----------------
__global__ __launch_bounds__(256) void gemm_mfma(const __hip_bfloat16* __restrict__ Eb,
                                                 float* __restrict__ S,
                                                 float* __restrict__ rsum,
                                                 float* __restrict__ rsumsq,
                                                 int n) {
    int bx = blockIdx.x, by = blockIdx.y;
    if (bx < by) return;
    __shared__ float lds[4][64][65];
    int row0 = by * 128, col0 = bx * 128;
    int tid = threadIdx.x, lane = tid & 63, wid = tid >> 6;
    int wr = wid >> 1, wc = wid & 1;
    int rbase = row0 + wr * 64 + (lane & 15);
    int cbase = col0 + wc * 64 + (lane & 15);
    int kg2 = ((lane >> 4) * 8) * 2;
    const char* Ep = (const char*)Eb;
    unsigned aoff[4], boff[4];
#pragma unroll
    for (int i = 0; i < 4; ++i) {
        aoff[i] = (unsigned)min(rbase + i * 16, n - 1) * (ISZ * 2) + kg2;
        boff[i] = (unsigned)min(cbase + i * 16, n - 1) * (ISZ * 2) + kg2;
    }
    f32x4 acc[4][4] = {};
#pragma unroll
    for (int kt = 0; kt < ISZ; kt += 32) {
        bf16x8 a[4], b[4];
#pragma unroll
        for (int i = 0; i < 4; ++i) a[i] = *(const bf16x8*)(Ep + aoff[i] + kt * 2);
#pragma unroll
        for (int j = 0; j < 4; ++j) b[j] = *(const bf16x8*)(Ep + boff[j] + kt * 2);
#pragma unroll
        for (int i = 0; i < 4; ++i)
#pragma unroll
            for (int j = 0; j < 4; ++j)
                acc[i][j] = __builtin_amdgcn_mfma_f32_16x16x32_bf16(a[i], b[j], acc[i][j], 0, 0, 0);
    }
    float (*T)[65] = lds[wid];   // wave-private
#pragma unroll
    for (int i = 0; i < 4; ++i)
#pragma unroll
        for (int j = 0; j < 4; ++j)
#pragma unroll
            for (int r = 0; r < 4; ++r)
                T[(lane >> 4) * 4 + i * 16 + r][(lane & 15) + j * 16] = acc[i][j][r];
    int gr0 = row0 + wr * 64;
    int gc0 = col0 + wc * 64;
    int c4 = (lane & 15) * 4;
#pragma unroll
    for (int p = 0; p < 16; ++p) {
        int r = p * 4 + (lane >> 4);
        int gr = gr0 + r;
        if (gr >= n) continue;
        int gc = gc0 + c4;
        float4 w = make_float4(T[r][c4], T[r][c4 + 1], T[r][c4 + 2], T[r][c4 + 3]);
        if (gc + 3 < n) {
            *(float4*)&S[(size_t)gr * n + gc] = w;
        } else {
            float wa[4] = {w.x, w.y, w.z, w.w};
#pragma unroll
            for (int q = 0; q < 4; ++q)
                if (gc + q < n) S[(size_t)gr * n + gc + q] = wa[q];
        }
    }
    {
        int gr = gr0 + lane;
        if (gr < n) {
            float s1 = 0.0f, s2 = 0.0f;
            int cmax = min(64, n - gc0);
            for (int c = 0; c < cmax; ++c) { float x = T[lane][c]; s1 += x; s2 += x * x; }
            if (cmax > 0) { atomicAdd(&rsum[gr], s1); atomicAdd(&rsumsq[gr], s2); }
        }
    }
    if (bx > by) {
#pragma unroll
        for (int p = 0; p < 16; ++p) {
            int rp = p * 4 + (lane >> 4);
            int gr2 = gc0 + rp;
            if (gr2 >= n) continue;
            int gc2 = gr0 + c4;
            float4 w = make_float4(T[c4][rp], T[c4 + 1][rp], T[c4 + 2][rp], T[c4 + 3][rp]);
            if (gc2 + 3 < n) {
                *(float4*)&S[(size_t)gr2 * n + gc2] = w;
            } else {
                float wa[4] = {w.x, w.y, w.z, w.w};
#pragma unroll
                for (int q = 0; q < 4; ++q)
                    if (gc2 + q < n) S[(size_t)gr2 * n + gc2 + q] = wa[q];
            }
        }
        int gr2 = gc0 + lane;
        if (gr2 < n) {
            float s1 = 0.0f, s2 = 0.0f;
            int rmax = min(64, n - gr0);
            for (int r = 0; r < rmax; ++r) { float x = T[r][lane]; s1 += x; s2 += x * x; }
            if (rmax > 0) { atomicAdd(&rsum[gr2], s1); atomicAdd(&rsumsq[gr2], s2); }
        }
    }
}

// R24-proven topk: launch_bounds(256,8), fused zeroing, stats from gemm,
// collect -> stored lex rank -> borderline-band fp64 -> exact rank -> patches.
template <bool ZEROFILL>
__global__ __launch_bounds__(256, 8) void topk_mask(const float* SIM, float* OUT,
                                                    const float* __restrict__ F,
                                                    const float* __restrict__ W0,
                                                    const float* __restrict__ W1,
                                                    const double* __restrict__ snorm,
                                                    const float* __restrict__ rsum,
                                                    const float* __restrict__ rsumsq,
                                                    int n) {
    __shared__ unsigned flags[320];
    __shared__ int redi[4];
    __shared__ int cand_idx[NCAND];
    __shared__ float csim[NCAND];
    __shared__ int selc[NSEL];
    __shared__ int blist[NBL];
    __shared__ double cand_val[NSEL];
    __shared__ int rankarr[NSEL];
    __shared__ int ncand, nhi_s, nbl_s;
    __shared__ float s31_s;
    int row = blockIdx.x;
    int tid = threadIdx.x;
    int lane = tid & 63, wid = tid >> 6;
    const float* simp = SIM + (size_t)row * n;
    float* outp = OUT + (size_t)row * n;

    float rs = rsum[row];
    float rq = rsumsq[row];

    if constexpr (ZEROFILL) {
        float4 z4 = make_float4(0.f, 0.f, 0.f, 0.f);
#pragma unroll
        for (int s = 0; s < 10; ++s) {
            int e = 4 * tid + 1024 * s;
            if (e < n) *(float4*)(outp + e) = z4;
        }
    }
    float v[40];
#pragma unroll
    for (int s = 0; s < 10; ++s) {
        int e = 4 * tid + 1024 * s;
        if (e < n) {
            float4 w = *(const float4*)(simp + e);
            v[s * 4 + 0] = w.x; v[s * 4 + 1] = w.y;
            v[s * 4 + 2] = w.z; v[s * 4 + 3] = w.w;
        } else {
#pragma unroll
            for (int q = 0; q < 4; ++q) v[s * 4 + q] = -1e30f;
        }
    }
    if constexpr (!ZEROFILL)
        for (int q = tid; q < 320; q += 256) flags[q] = 0;
    if (tid == 0) { ncand = 0; nhi_s = 0; nbl_s = 0; }
    __syncthreads();

    float mean = rs / (float)n;
    float var = fmaxf(rq / (float)n - mean * mean, 1e-12f);
    float thr = mean + ZSTAT * sqrtf(var);

    auto blockcount = [&](float t) -> int {
        int c = 0;
#pragma unroll
        for (int q = 0; q < 40; ++q) c += (v[q] >= t) ? 1 : 0;
#pragma unroll
        for (int off = 32; off; off >>= 1) c += __shfl_down(c, off);
        if (lane == 0) redi[wid] = c;
        __syncthreads();
        int tot = redi[0] + redi[1] + redi[2] + redi[3];
        __syncthreads();
        return tot;
    };
    auto collect = [&](float t) {
#pragma unroll
        for (int s = 0; s < 10; ++s) {
            int e = 4 * tid + 1024 * s;
#pragma unroll
            for (int j = 0; j < 4; ++j) {
                float x = v[s * 4 + j];
                if (x >= t) {
                    int pos = atomicAdd(&ncand, 1);
                    if (pos < NCAND) { cand_idx[pos] = e + j; csim[pos] = x; }
                }
            }
        }
        __syncthreads();
    };

    collect(thr);
    if (ncand < CMIN || ncand > NCAND) {
        __syncthreads();
        if (tid == 0) ncand = 0;
        __syncthreads();
        float lo = 0.0f, hi = 0.75f;
        thr = 0.0f;
        bool found = false;
        for (int it = 0; it < 30 && !found; ++it) {
            float mid = 0.5f * (lo + hi);
            int c = blockcount(mid);
            if (c >= CMIN && c <= CEXIT) { thr = mid; found = true; }
            else if (c >= CMIN) lo = mid;
            else hi = mid;
        }
        if (!found) thr = lo;
        collect(thr);
    }
    int m = min(ncand, NCAND);

    for (int c = tid; c < m; c += 256) {
        float mys = csim[c]; int myi = cand_idx[c]; int r = 0;
        for (int j = 0; j < m; ++j) {
            float vj = csim[j];
            r += (vj > mys || (vj == mys && cand_idx[j] < myi)) ? 1 : 0;
        }
        if (r < NSEL) selc[r] = c;
        if (r == KSEL - 1) s31_s = mys;
    }
    __syncthreads();
    float s31 = s31_s;

    for (int c = tid; c < m; c += 256) {
        float sc = csim[c];
        if (sc > s31 + WIN) atomicAdd(&nhi_s, 1);
        else if (sc >= s31 - WIN) { int p = atomicAdd(&nbl_s, 1); if (p < NBL) blist[p] = c; }
    }
    __syncthreads();
    int nhi = nhi_s, nblv = nbl_s;
    bool fastB = (nblv <= NBL);
    int mm = fastB ? nblv : min(m, NSEL);
    int kneed = KSEL - nhi;

    double hr[4];
    float w0e[4], w1e[4];
#pragma unroll
    for (int r = 0; r < 4; ++r) {
        int e = lane + 64 * r;
        w0e[r] = W0[e];
        w1e[r] = W1[e];
        hr[r] = h64_of(F[(size_t)row * ISZ + e], w0e[r], w1e[r]);
    }
    double srow = snorm[row];
    for (int s = wid * 4; s < mm; s += 16) {
        int l0 = fastB ? blist[s] : selc[s];
        int l1 = fastB ? blist[min(s + 1, mm - 1)] : selc[min(s + 1, mm - 1)];
        int l2 = fastB ? blist[min(s + 2, mm - 1)] : selc[min(s + 2, mm - 1)];
        int l3 = fastB ? blist[min(s + 3, mm - 1)] : selc[min(s + 3, mm - 1)];
        int j0 = cand_idx[l0], j1 = cand_idx[l1], j2 = cand_idx[l2], j3 = cand_idx[l3];
        double a0 = 0.0, a1 = 0.0, a2 = 0.0, a3 = 0.0;
#pragma unroll
        for (int r = 0; r < 4; ++r) {
            int e = lane + 64 * r;
            float f0 = F[(size_t)j0 * ISZ + e];
            float f1 = F[(size_t)j1 * ISZ + e];
            float f2 = F[(size_t)j2 * ISZ + e];
            float f3 = F[(size_t)j3 * ISZ + e];
            a0 += hr[r] * h64_of(f0, w0e[r], w1e[r]);
            a1 += hr[r] * h64_of(f1, w0e[r], w1e[r]);
            a2 += hr[r] * h64_of(f2, w0e[r], w1e[r]);
            a3 += hr[r] * h64_of(f3, w0e[r], w1e[r]);
        }
#pragma unroll
        for (int off = 32; off; off >>= 1) {
            a0 += __shfl_down(a0, off);
            a1 += __shfl_down(a1, off);
            a2 += __shfl_down(a2, off);
            a3 += __shfl_down(a3, off);
        }
        if (lane == 0) {
            cand_val[s] = a0 / (srow * snorm[j0]);
            if (s + 1 < mm) cand_val[s + 1] = a1 / (srow * snorm[j1]);
            if (s + 2 < mm) cand_val[s + 2] = a2 / (srow * snorm[j2]);
            if (s + 3 < mm) cand_val[s + 3] = a3 / (srow * snorm[j3]);
        }
    }
    __syncthreads();

    int keepthr = fastB ? kneed : KSEL;
    for (int s2 = tid; s2 < mm; s2 += 256) {
        int li = fastB ? blist[s2] : selc[s2];
        double vv = cand_val[s2];
        int idx = cand_idx[li];
        int rank = 0;
        for (int j2 = 0; j2 < mm; ++j2) {
            int lj = fastB ? blist[j2] : selc[j2];
            double vj = cand_val[j2];
            rank += (vj > vv || (vj == vv && cand_idx[lj] < idx)) ? 1 : 0;
        }
        rankarr[s2] = rank;
        if constexpr (!ZEROFILL) {
            if (rank < keepthr) atomicOr(&flags[idx >> 5], 1u << (idx & 31));
        }
    }
    if constexpr (!ZEROFILL) {
        if (fastB) {
            for (int c = tid; c < m; c += 256) {
                if (csim[c] > s31 + WIN) {
                    int idx = cand_idx[c];
                    atomicOr(&flags[idx >> 5], 1u << (idx & 31));
                }
            }
        }
    }
    __syncthreads();

    if constexpr (!ZEROFILL) {
#pragma unroll
        for (int s = 0; s < 10; ++s) {
            int e = 4 * tid + 1024 * s;
            if (e >= n) continue;
            float vals[4] = {v[s * 4 + 0], v[s * 4 + 1], v[s * 4 + 2], v[s * 4 + 3]};
            float o[4];
#pragma unroll
            for (int j = 0; j < 4; ++j) {
                int q = e + j;
                bool keep = (flags[q >> 5] >> (q & 31)) & 1u;
                o[j] = (keep && vals[j] > 0.0f) ? vals[j] : 0.0f;
            }
            *(float4*)(outp + e) = make_float4(o[0], o[1], o[2], o[3]);
        }
        __syncthreads();
    }

    if (fastB) {
        for (int c = tid; c < m; c += 256)
            if (csim[c] > s31 + WIN) outp[cand_idx[c]] = fmaxf(csim[c], 0.0f);
        for (int s2 = tid; s2 < mm; s2 += 256)
            if (rankarr[s2] < kneed)
                outp[cand_idx[blist[s2]]] = (float)fmax(cand_val[s2], 0.0);
    } else {
        for (int s2 = tid; s2 < mm; s2 += 256)
            if (rankarr[s2] < KSEL)
                outp[cand_idx[selc[s2]]] = (float)fmax(cand_val[s2], 0.0);
    }
}

extern "C" void kernel_launch(void* const* d_in, const int* in_sizes, int n_in,
                              void* d_out, int out_size, void* d_ws, size_t ws_size,
                              hipStream_t stream) {
    const float* F  = (const float*)d_in[0];
    const float* w0 = (const float*)d_in[1];
    const float* w1 = (const float*)d_in[2];
    float* out = (float*)d_out;
    int isz = in_sizes[1];           // 256
    int n = in_sizes[0] / isz;       // 10000

    char* ws = (char*)d_ws;
    __hip_bfloat16* Ebf = (__hip_bfloat16*)ws;                       // 5.12 MB
    size_t o_snorm = (size_t)n * ISZ * 2;
    double* snorm = (double*)(ws + o_snorm);                         // 80 KB
    size_t o_rsum = o_snorm + (size_t)n * 8;
    float* rsum = (float*)(ws + o_rsum);                             // 40 KB
    float* rsumsq = (float*)(ws + o_rsum + (size_t)n * 4);           // 40 KB
    size_t o_sim = (o_rsum + (size_t)n * 8 + 255) & ~(size_t)255;
    size_t need = o_sim + (size_t)n * n * 4;                         // +400 MB

    int nt = (n + 127) / 128;
    emb_kernel<<<n, 256, 0, stream>>>(F, w0, w1, Ebf, snorm, n);
    hipMemsetAsync(rsum, 0, (size_t)n * 8, stream);
    if (ws_size >= need) {
        float* S = (float*)(ws + o_sim);
        gemm_mfma<<<dim3(nt, nt), 256, 0, stream>>>(Ebf, S, rsum, rsumsq, n);
        topk_mask<true><<<n, 256, 0, stream>>>(S, out, F, w0, w1, snorm, rsum, rsumsq, n);
    } else {
        gemm_mfma<<<dim3(nt, nt), 256, 0, stream>>>(Ebf, out, rsum, rsumsq, n);
        topk_mask<false><<<n, 256, 0, stream>>>(out, out, F, w0, w1, snorm, rsum, rsumsq, n);
    }
}